// Round 12
// baseline (179.783 us; speedup 1.0000x reference)
//
#include <hip/hip_runtime.h>

// YOLOv7 P3 head (stride 8): B=16, A=3, NC=80, H=W=80.
// Input  (b, a*85, h, w) channel-major fp32.
// Output (b, a*h*w, 85)  fp32: [px,py,pw,ph,conf,cls*80].
//
// v13 = v11 + NONTEMPORAL STORES (completes the cache-policy 2x2).
// Ledger: {cached,cached}=63.5 (v5), {cached ld, nt st}=63.5 (v1),
// {nt ld, cached st}=~58 (v11, first real win: reads no longer thrash
// L2 against the write stream). Untested cell: {nt,nt}. Writes are
// full-line 1KB bursts per instr -> L2 write-combining buys nothing;
// nt stores skip the allocate-age-evict churn of 102MB through the
// 32MB aggregate L2. Structural levers (MLP, barriers, occupancy,
// segments 64B-1280B, persistent pipelining) all refuted in both
// cache regimes; traffic is compulsory (poison fill wipes L3 between
// iterations).
//
// One block per (b,a,y): output block = 6800 contiguous floats.
// 512 threads/block: 4 blocks x 8 waves = 32 waves/CU.

#define A_    3
#define H_    80
#define W_    80
#define CH_   85            // 5 + 80 classes
#define TILE_ (CH_ * W_)    // 6800 floats per (b,a,y)
#define VEC_  (TILE_ / 4)   // 1700 float4

typedef float f32x4 __attribute__((ext_vector_type(4)));

__device__ __forceinline__ float fast_sigmoid(float x) {
    return __builtin_amdgcn_rcpf(1.0f + __expf(-x));
}

__global__ __launch_bounds__(512) void yolo_head_kernel(
    const float* __restrict__ in,
    const float* __restrict__ anchors,
    float* __restrict__ out)
{
    __shared__ float lds[TILE_];

    const int bid = blockIdx.x;        // (b*3 + a)*80 + y
    const int y   = bid % H_;
    const int ba  = bid / H_;          // b*3 + a
    const int a   = ba % A_;

    const float aw = anchors[2 * a];
    const float ah = anchors[2 * a + 1];
    const float fy = (float)y;
    const int   t  = threadIdx.x;

    // ---- Phase 1a: 4 nontemporal f32x4 loads (no cache allocation) ----
    // in[(ba*85 + ch)*6400 + y*80 + x], x = 4*xq + j
    const float* in_row = in + (size_t)(ba * CH_) * (H_ * W_) + y * W_;

    f32x4 v[4];
    int   chv[4], xqv[4];
#pragma unroll
    for (int k = 0; k < 4; ++k) {
        int i = k * 512 + t;               // i = ch*20 + xq
        i = (i < VEC_) ? i : (VEC_ - 1);   // clamp: tail lanes re-load last quad
        int ch = i / 20;
        int xq = i - ch * 20;
        chv[k] = ch;
        xqv[k] = xq;
        v[k] = __builtin_nontemporal_load(
                   (const f32x4*)(in_row + ch * (H_ * W_) + 4 * xq));
    }
    __builtin_amdgcn_sched_barrier(0);

    // ---- Phase 1b: transform -> LDS (x-major, output order lds[x*85+ch])
#pragma unroll
    for (int k = 0; k < 4; ++k) {
        int i = k * 512 + t;
        if (i < VEC_) {
            int ch = chv[k];
            int xq = xqv[k];
            f32x4 w = v[k];
            float r[4];
            if (ch >= 4) {
                r[0] = fast_sigmoid(w.x);
                r[1] = fast_sigmoid(w.y);
                r[2] = fast_sigmoid(w.z);
                r[3] = fast_sigmoid(w.w);
            } else if (ch == 0) {
                float x0 = (float)(4 * xq);
                r[0] = (fast_sigmoid(w.x) + x0)        * 8.0f;  // px
                r[1] = (fast_sigmoid(w.y) + x0 + 1.0f) * 8.0f;
                r[2] = (fast_sigmoid(w.z) + x0 + 2.0f) * 8.0f;
                r[3] = (fast_sigmoid(w.w) + x0 + 3.0f) * 8.0f;
            } else if (ch == 1) {
                r[0] = (fast_sigmoid(w.x) + fy) * 8.0f;         // py
                r[1] = (fast_sigmoid(w.y) + fy) * 8.0f;
                r[2] = (fast_sigmoid(w.z) + fy) * 8.0f;
                r[3] = (fast_sigmoid(w.w) + fy) * 8.0f;
            } else {
                float s = (ch == 2) ? aw : ah;                  // pw / ph
                r[0] = __expf(fminf(fmaxf(w.x, -16.0f), 16.0f)) * s;
                r[1] = __expf(fminf(fmaxf(w.y, -16.0f), 16.0f)) * s;
                r[2] = __expf(fminf(fmaxf(w.z, -16.0f), 16.0f)) * s;
                r[3] = __expf(fminf(fmaxf(w.w, -16.0f), 16.0f)) * s;
            }
            int base = 4 * xq * CH_ + ch;   // lds[(4*xq+j)*85 + ch]
#pragma unroll
            for (int j = 0; j < 4; ++j)
                lds[base + j * CH_] = r[j];
        }
    }
    __syncthreads();

    // ---- Phase 2: LDS -> out, contiguous 16B nontemporal stores ----
    f32x4*       out4 = (f32x4*)(out + (size_t)bid * TILE_);
    const f32x4* lds4 = (const f32x4*)lds;

    f32x4 o[4];
#pragma unroll
    for (int k = 0; k < 4; ++k) {
        int c = k * 512 + t;
        c = (c < VEC_) ? c : (VEC_ - 1);
        o[k] = lds4[c];
    }
    __builtin_amdgcn_sched_barrier(0);
#pragma unroll
    for (int k = 0; k < 4; ++k) {
        int c = k * 512 + t;
        if (c < VEC_) {
            __builtin_nontemporal_store(o[k], &out4[c]);
        }
    }
}

extern "C" void kernel_launch(void* const* d_in, const int* in_sizes, int n_in,
                              void* d_out, int out_size, void* d_ws, size_t ws_size,
                              hipStream_t stream) {
    const float* in      = (const float*)d_in[0];   // (16, 255, 80, 80) fp32
    const float* anchors = (const float*)d_in[1];   // (3, 2) fp32
    float*       out     = (float*)d_out;           // (16, 19200, 85) fp32

    const int blocks = 16 * A_ * H_;                // 3840: one per (b,a,y)
    yolo_head_kernel<<<blocks, 512, 0, stream>>>(in, anchors, out);
}